// Round 3
// baseline (222.537 us; speedup 1.0000x reference)
//
#include <hip/hip_runtime.h>

// R9: Q-projection fused INTO attn (each 16x64 Q-tile consumed by exactly one
// wave -> zero duplication; ~96 MFMA/wave hidden under the 402.7MB write drain).
//  - proj shrinks to K-only: grid (32,6), half FLOPs, Kh[4096][768] f16
//  - attn: per-wave Q-GEMM (Xh rows x WtQ rows, 24 K-steps x 4 tiles), then
//    scale+bias+f16-pack and 16x shfl to rebuild the B-fragment layout
//    (lane quad needs d in [quad*8,quad*8+8): t16=quad>>1, src quads 2(q&1),+1)
//  - QK^T / blend / softmax / direct float4 stores unchanged from R8
// prep unchanged. Numerics identical (same MFMA chain + (acc+bq)*0.9/8).

typedef _Float16 f16;
typedef _Float16 f16x4 __attribute__((ext_vector_type(4)));
typedef _Float16 f16x8 __attribute__((ext_vector_type(8)));
typedef float    f32x4 __attribute__((ext_vector_type(4)));
typedef unsigned int u32;

#define NTOK   512
#define DMODEL 768
#define BATCH  8
#define NHEAD  12
#define NEGV   (-1e9f)
#define DEPS   516   // dep LDS row stride (floats)

#define GLOAD_LDS16(g, l)                                                        \
    __builtin_amdgcn_global_load_lds(                                            \
        (const __attribute__((address_space(1))) void*)(g),                      \
        (__attribute__((address_space(3))) void*)(l), 16, 0, 0)

// ---------------------------------------------------------------------------
// prep: blocks [0,3072) convert X fp32->f16; blocks [3072,4224) transpose
// Wq/Wk 32x32 tiles -> Wt[n][k] f16 (rows 0-767 Wq^T, 768-1535 Wk^T).
__global__ __launch_bounds__(256)
void prep_kernel(const float* __restrict__ X, f16* __restrict__ Xh,
                 const float* __restrict__ Wq, const float* __restrict__ Wk,
                 f16* __restrict__ Wt) {
    const int bx = blockIdx.x;
    if (bx < 3072) {
        const size_t i = ((size_t)bx * 256 + threadIdx.x) * 4;
        float4 v = *(const float4*)&X[i];
        f16x4 h = { (f16)v.x, (f16)v.y, (f16)v.z, (f16)v.w };
        *(f16x4*)&Xh[i] = h;
    } else {
        __shared__ float tile[32][33];
        const int id = bx - 3072;
        const int kb = (id % 24) * 32;
        const int nb = (id / 24) * 32;
        const float* __restrict__ W = (nb < 768) ? Wq : Wk;
        const int nc = (nb < 768) ? nb : nb - 768;
        const int tx = threadIdx.x & 31, ty = threadIdx.x >> 5;
        #pragma unroll
        for (int i = 0; i < 4; ++i)
            tile[ty + i*8][tx] = W[(size_t)(kb + ty + i*8) * DMODEL + nc + tx];
        __syncthreads();
        #pragma unroll
        for (int i = 0; i < 4; ++i)
            Wt[(size_t)(nb + ty + i*8) * DMODEL + kb + tx] = (f16)tile[tx][ty + i*8];
    }
}

// ---------------------------------------------------------------------------
// projK: K-only projection. 128x128 tile, grid (32,6). global_load_lds staging
// (R8 pattern, linear LDS). Kh[4096][768] = Xh * WtK^T + bk.
__global__ __launch_bounds__(256)
void projk_mfma(const f16* __restrict__ Xh, const f16* __restrict__ Wt,
                const float* __restrict__ bk, f16* __restrict__ Kh) {
    const int m0 = blockIdx.x * 128;
    const int n0 = blockIdx.y * 128;           // 0..640 (K cols)
    const int tid = threadIdx.x;
    const int wid = tid >> 6, l = tid & 63;
    const int l15 = l & 15, quad = l >> 4;
    const int wm = (wid & 1) * 64;
    const int wn = (wid >> 1) * 64;

    __shared__ f16 As[128 * 64];
    __shared__ f16 Bs[128 * 64];

    f32x4 acc[4][4];
    #pragma unroll
    for (int i = 0; i < 4; ++i)
        #pragma unroll
        for (int j = 0; j < 4; ++j) acc[i][j] = (f32x4){0.f, 0.f, 0.f, 0.f};

    const int crow = l >> 3;
    const int ccol = (l & 7) * 8;   // halfs

    for (int kt = 0; kt < DMODEL; kt += 64) {
        #pragma unroll
        for (int i = 0; i < 4; ++i) {
            const int c   = wid * 4 + i;
            const int row = c * 8 + crow;
            GLOAD_LDS16(Xh + (size_t)(m0 + row) * DMODEL + kt + ccol, &As[c * 512]);
            GLOAD_LDS16(Wt + (size_t)(768 + n0 + row) * DMODEL + kt + ccol, &Bs[c * 512]);
        }
        __syncthreads();
        #pragma unroll
        for (int ks = 0; ks < 2; ++ks) {
            f16x8 a[4], b[4];
            #pragma unroll
            for (int mi = 0; mi < 4; ++mi)
                a[mi] = *(f16x8*)&As[(wm + mi*16 + l15) * 64 + ks*32 + quad*8];
            #pragma unroll
            for (int ni = 0; ni < 4; ++ni)
                b[ni] = *(f16x8*)&Bs[(wn + ni*16 + l15) * 64 + ks*32 + quad*8];
            #pragma unroll
            for (int mi = 0; mi < 4; ++mi)
                #pragma unroll
                for (int ni = 0; ni < 4; ++ni)
                    acc[mi][ni] = __builtin_amdgcn_mfma_f32_16x16x32_f16(
                        a[mi], b[ni], acc[mi][ni], 0, 0, 0);
        }
        __syncthreads();
    }

    #pragma unroll
    for (int ni = 0; ni < 4; ++ni) {
        const int col = n0 + wn + ni * 16 + l15;
        const float bv = bk[col];
        #pragma unroll
        for (int mi = 0; mi < 4; ++mi)
            #pragma unroll
            for (int r = 0; r < 4; ++r) {
                const int row = m0 + wm + mi * 16 + quad * 4 + r;
                Kh[(size_t)row * DMODEL + col] = (f16)(acc[mi][ni][r] + bv);
            }
    }
}

// ---------------------------------------------------------------------------
// attn: block = (b, qt, head-group); 384 thr = 6 waves, wave w -> head hg*6+w.
// Phase 1: per-wave Q-proj (16 rows x 64 cols, K=768) from Xh/WtQ, swapped
//   mfma(WtQ, Xh): lane holds Q[q=l15][d = h*64 + t16*16 + quad*4 + r].
// Phase 2: scale+bias -> f16 pack -> 16x shfl to B-fragment layout.
// Phase 3: QK^T swapped mfma(K, Q), blend/mask/softmax, direct float4 stores.
__global__ __launch_bounds__(384, 2)
void attn_mfma(const f16* __restrict__ Xh, const f16* __restrict__ Wt,
               const float* __restrict__ bq, const f16* __restrict__ Kh,
               const float* __restrict__ dep, const int* __restrict__ mask,
               float* __restrict__ out) {
    const int qt = blockIdx.x;        // 0..31
    const int hg = blockIdx.y;        // 0..1
    const int b  = blockIdx.z;        // 0..7
    const int tid = threadIdx.x;
    const int wid = tid >> 6;         // 0..5
    const int l   = tid & 63;
    const int l15 = l & 15, quad = l >> 4;
    const int h  = hg * 6 + wid;
    const int q0 = qt * 16;

    __shared__ float depL[16 * DEPS];        // 33.0 KB

    // stage dep tile (barrier deferred past all MFMA phases)
    {
        const float* __restrict__ src = dep + ((size_t)b * NTOK + q0) * NTOK;
        #pragma unroll
        for (int i = 0; i < 6; ++i) {
            const int idx = tid + i * 384;
            if (idx < 2048) {
                const int row = idx >> 7, c4 = idx & 127;
                float4 v = *(const float4*)&src[(size_t)row * NTOK + c4 * 4];
                *(float4*)&depL[row * DEPS + c4 * 4] = v;
            }
        }
    }

    // ---- Phase 1: Q-proj. accq[t16][r] = Q[q0+l15][h*64 + t16*16 + quad*4 + r]
    f32x4 accq[4];
    #pragma unroll
    for (int t = 0; t < 4; ++t) accq[t] = (f32x4){0.f, 0.f, 0.f, 0.f};
    {
        const f16* __restrict__ xb = Xh + ((size_t)(b * NTOK + q0 + l15)) * DMODEL + quad * 8;
        const f16* __restrict__ wb = Wt + ((size_t)(h * 64 + l15)) * DMODEL + quad * 8;
        #pragma unroll 4
        for (int kt = 0; kt < 24; ++kt) {
            const f16x8 xf = *(const f16x8*)(xb + kt * 32);
            #pragma unroll
            for (int t16 = 0; t16 < 4; ++t16) {
                const f16x8 af = *(const f16x8*)(wb + (size_t)(t16 * 16) * DMODEL + kt * 32);
                accq[t16] = __builtin_amdgcn_mfma_f32_16x16x32_f16(af, xf, accq[t16], 0, 0, 0);
            }
        }
    }

    // ---- Phase 2: (acc+bq)*0.9/8 -> f16, then shuffle into B-fragment layout.
    const float SC = (1.0f - 0.1f) / 8.0f;
    uint2 qh[4];
    #pragma unroll
    for (int t16 = 0; t16 < 4; ++t16) {
        const int dbase = h * 64 + t16 * 16 + quad * 4;
        union { uint2 u; f16x4 hv; } p;
        #pragma unroll
        for (int r = 0; r < 4; ++r)
            p.hv[r] = (f16)((accq[t16][r] + bq[dbase + r]) * SC);
        qh[t16] = p.u;
    }
    // lane (l15,quad) needs d-offsets [quad*8, quad*8+8) and +32:
    //   t16 = quad>>1 (+2 for qf1), source quads 2*(quad&1), 2*(quad&1)+1.
    const int srcA = l15 + ((quad & 1) << 5);   // lane of quad 2*(quad&1)
    const int srcB = srcA + 16;
    #define SH(v, s) ((u32)__shfl((int)(v), (s)))
    const bool hi = (quad >> 1) != 0;
    u32 a0x = SH(qh[0].x, srcA), a0y = SH(qh[0].y, srcA);
    u32 a1x = SH(qh[1].x, srcA), a1y = SH(qh[1].y, srcA);
    u32 b0x = SH(qh[0].x, srcB), b0y = SH(qh[0].y, srcB);
    u32 b1x = SH(qh[1].x, srcB), b1y = SH(qh[1].y, srcB);
    union { uint4 u; f16x8 hv; } u0;
    u0.u.x = hi ? a1x : a0x;  u0.u.y = hi ? a1y : a0y;
    u0.u.z = hi ? b1x : b0x;  u0.u.w = hi ? b1y : b0y;
    const f16x8 qf0 = u0.hv;
    u32 c2x = SH(qh[2].x, srcA), c2y = SH(qh[2].y, srcA);
    u32 c3x = SH(qh[3].x, srcA), c3y = SH(qh[3].y, srcA);
    u32 d2x = SH(qh[2].x, srcB), d2y = SH(qh[2].y, srcB);
    u32 d3x = SH(qh[3].x, srcB), d3y = SH(qh[3].y, srcB);
    union { uint4 u; f16x8 hv; } u1;
    u1.u.x = hi ? c3x : c2x;  u1.u.y = hi ? c3y : c2y;
    u1.u.z = hi ? d3x : d2x;  u1.u.w = hi ? d3y : d2y;
    const f16x8 qf1 = u1.hv;
    #undef SH

    // ---- Phase 3: QK^T swapped mfma(K, Q). lane: q=l15, k = 16t + 4*quad + r.
    f32x4 acc[32];
    #pragma unroll
    for (int t = 0; t < 32; ++t) acc[t] = (f32x4){0.f, 0.f, 0.f, 0.f};

    const f16* __restrict__ Kb = Kh + (size_t)(b * NTOK + l15) * DMODEL + h * 64 + quad * 8;
    #pragma unroll
    for (int t = 0; t < 32; ++t) {
        f16x8 k0 = *(const f16x8*)(Kb + (size_t)(t * 16) * DMODEL);
        acc[t] = __builtin_amdgcn_mfma_f32_16x16x32_f16(k0, qf0, acc[t], 0, 0, 0);
        f16x8 k1 = *(const f16x8*)(Kb + (size_t)(t * 16) * DMODEL + 32);
        acc[t] = __builtin_amdgcn_mfma_f32_16x16x32_f16(k1, qf1, acc[t], 0, 0, 0);
    }

    __syncthreads();   // dep tile staged by all waves

    // blend (float4 dep from LDS) + mask + row-max, single pass.
    const float DW = 0.1f;
    const int* __restrict__ mrow = mask + b * NTOK;
    float m = NEGV;
    #pragma unroll
    for (int t = 0; t < 32; ++t) {
        const int kc = t * 16 + quad * 4;
        const f32x4 dv = *(const f32x4*)&depL[l15 * DEPS + kc];
        const int4  mv = *(const int4*)&mrow[kc];
        const float s0 = acc[t][0] + DW * dv[0];
        const float s1 = acc[t][1] + DW * dv[1];
        const float s2 = acc[t][2] + DW * dv[2];
        const float s3 = acc[t][3] + DW * dv[3];
        acc[t][0] = mv.x ? s0 : NEGV;
        acc[t][1] = mv.y ? s1 : NEGV;
        acc[t][2] = mv.z ? s2 : NEGV;
        acc[t][3] = mv.w ? s3 : NEGV;
        m = fmaxf(m, fmaxf(fmaxf(acc[t][0], acc[t][1]), fmaxf(acc[t][2], acc[t][3])));
    }
    m = fmaxf(m, __shfl_xor(m, 16));
    m = fmaxf(m, __shfl_xor(m, 32));

    float sum = 0.f;
    #pragma unroll
    for (int t = 0; t < 32; ++t) {
        #pragma unroll
        for (int r = 0; r < 4; ++r) {
            const float e = __expf(acc[t][r] - m);
            acc[t][r] = e;
            sum += e;
        }
    }
    sum += __shfl_xor(sum, 16);
    sum += __shfl_xor(sum, 32);
    const float inv = 1.0f / sum;

    // epilogue: direct float4 stores. out[b][h][q0+l15][16t + 4*quad + r]
    const size_t obase = ((size_t)((b * NHEAD + h) * NTOK) + q0 + l15) * NTOK + quad * 4;
    #pragma unroll
    for (int t = 0; t < 32; ++t) {
        f32x4 v = acc[t] * inv;
        *(f32x4*)&out[obase + (size_t)t * 16] = v;
    }
}

// ---------------------------------------------------------------------------
extern "C" void kernel_launch(void* const* d_in, const int* in_sizes, int n_in,
                              void* d_out, int out_size, void* d_ws, size_t ws_size,
                              hipStream_t stream) {
    const float* X    = (const float*)d_in[0];
    const int*   mask = (const int*)  d_in[1];
    const float* dep  = (const float*)d_in[2];
    const float* Wq   = (const float*)d_in[3];
    const float* bq   = (const float*)d_in[4];
    const float* Wk   = (const float*)d_in[5];
    const float* bk   = (const float*)d_in[6];
    float* out = (float*)d_out;

    f16* Xh = (f16*)d_ws;                                  // 4096*768
    f16* Wt = Xh + (size_t)BATCH * NTOK * DMODEL;          // 1536*768
    f16* Kh = Wt + (size_t)1536 * DMODEL;                  // 4096*768

    prep_kernel<<<dim3(3072 + 1152), 256, 0, stream>>>(X, Xh, Wq, Wk, Wt);
    projk_mfma<<<dim3(4096 / 128, 768 / 128), 256, 0, stream>>>(Xh, Wt, bk, Kh);
    attn_mfma<<<dim3(32, 2, BATCH), 384, 0, stream>>>(Xh, Wt, bq, Kh, dep, mask, out);
}

// Round 4
// 189.697 us; speedup vs baseline: 1.1731x; 1.1731x over previous
//
#include <hip/hip_runtime.h>

// R10: revert to R7 (best measured, 185.4us). R9's Q-proj fusion is a confirmed
// regression: attn 58 -> 97us, latency-bound (MfmaUtil 3.1%, VALUBusy 7.8%,
// 18% HBM) -- per-wave serial GEMM chains don't hide under the store drain.
// Budget model (fits R6-R9): fixed harness fills ~115 + attn 58 (402.7MB store
// floor = fill rate) + proj ~14 + prep ~5.
//  - attn: swapped mfma(K,Q) -> lane owns q=l15, k=16t+4quad+r; float4 dep
//    blend from LDS, 2-shfl softmax, direct float4 stores (at store floor)
//  - proj: 128x128 tile, reg-staged LDS (KPAD=72), 4 waves, BK=64
//  - prep: X fp32->f16 + Wq/Wk transpose

typedef _Float16 f16;
typedef _Float16 f16x4 __attribute__((ext_vector_type(4)));
typedef _Float16 f16x8 __attribute__((ext_vector_type(8)));
typedef float    f32x4 __attribute__((ext_vector_type(4)));

#define NTOK   512
#define DMODEL 768
#define BATCH  8
#define NHEAD  12
#define NEGV   (-1e9f)
#define KPAD   72    // proj LDS row stride (halfs)
#define DEPS   516   // dep LDS row stride (floats)

// ---------------------------------------------------------------------------
// prep: blocks [0,3072) convert X fp32->f16; blocks [3072,4224) transpose
// Wq/Wk 32x32 tiles -> Wt[n][k] f16 (rows 0-767 Wq^T, 768-1535 Wk^T).
__global__ __launch_bounds__(256)
void prep_kernel(const float* __restrict__ X, f16* __restrict__ Xh,
                 const float* __restrict__ Wq, const float* __restrict__ Wk,
                 f16* __restrict__ Wt) {
    const int bx = blockIdx.x;
    if (bx < 3072) {
        const size_t i = ((size_t)bx * 256 + threadIdx.x) * 4;
        float4 v = *(const float4*)&X[i];
        f16x4 h = { (f16)v.x, (f16)v.y, (f16)v.z, (f16)v.w };
        *(f16x4*)&Xh[i] = h;
    } else {
        __shared__ float tile[32][33];
        const int id = bx - 3072;
        const int kb = (id % 24) * 32;
        const int nb = (id / 24) * 32;
        const float* __restrict__ W = (nb < 768) ? Wq : Wk;
        const int nc = (nb < 768) ? nb : nb - 768;
        const int tx = threadIdx.x & 31, ty = threadIdx.x >> 5;
        #pragma unroll
        for (int i = 0; i < 4; ++i)
            tile[ty + i*8][tx] = W[(size_t)(kb + ty + i*8) * DMODEL + nc + tx];
        __syncthreads();
        #pragma unroll
        for (int i = 0; i < 4; ++i)
            Wt[(size_t)(nb + ty + i*8) * DMODEL + kb + tx] = (f16)tile[tx][ty + i*8];
    }
}

// ---------------------------------------------------------------------------
// proj: 128x128 tile per block, 4 waves in 2x2 quadrants, BK=64 LDS-staged.
// QK[4096][1536] = Xh * Wt^T + bias; Q columns (<768) pre-scaled by 0.9/8.
__global__ __launch_bounds__(256)
void proj_mfma(const f16* __restrict__ Xh, const f16* __restrict__ Wt,
               const float* __restrict__ bq, const float* __restrict__ bk,
               f16* __restrict__ QK) {
    const int m0 = blockIdx.x * 128;
    const int n0 = blockIdx.y * 128;
    const int tid = threadIdx.x;
    const int wid = tid >> 6, l = tid & 63;
    const int l15 = l & 15, quad = l >> 4;
    const int wm = (wid & 1) * 64;
    const int wn = (wid >> 1) * 64;

    __shared__ f16 As[128 * KPAD];
    __shared__ f16 Bs[128 * KPAD];

    f32x4 acc[4][4];
    #pragma unroll
    for (int i = 0; i < 4; ++i)
        #pragma unroll
        for (int j = 0; j < 4; ++j) acc[i][j] = (f32x4){0.f, 0.f, 0.f, 0.f};

    const int srow = tid >> 1;
    const int scol = (tid & 1) * 32;

    for (int kt = 0; kt < DMODEL; kt += 64) {
        const f16* __restrict__ Asrc = Xh + (size_t)(m0 + srow) * DMODEL + kt + scol;
        const f16* __restrict__ Bsrc = Wt + (size_t)(n0 + srow) * DMODEL + kt + scol;
        #pragma unroll
        for (int j = 0; j < 4; ++j) {
            f16x8 av = *(const f16x8*)(Asrc + j * 8);
            *(f16x8*)&As[srow * KPAD + scol + j * 8] = av;
        }
        #pragma unroll
        for (int j = 0; j < 4; ++j) {
            f16x8 bv = *(const f16x8*)(Bsrc + j * 8);
            *(f16x8*)&Bs[srow * KPAD + scol + j * 8] = bv;
        }
        __syncthreads();
        #pragma unroll
        for (int ks = 0; ks < 2; ++ks) {
            f16x8 a[4], b[4];
            #pragma unroll
            for (int mi = 0; mi < 4; ++mi)
                a[mi] = *(f16x8*)&As[(wm + mi*16 + l15) * KPAD + ks*32 + quad*8];
            #pragma unroll
            for (int ni = 0; ni < 4; ++ni)
                b[ni] = *(f16x8*)&Bs[(wn + ni*16 + l15) * KPAD + ks*32 + quad*8];
            #pragma unroll
            for (int mi = 0; mi < 4; ++mi)
                #pragma unroll
                for (int ni = 0; ni < 4; ++ni)
                    acc[mi][ni] = __builtin_amdgcn_mfma_f32_16x16x32_f16(
                        a[mi], b[ni], acc[mi][ni], 0, 0, 0);
        }
        __syncthreads();
    }

    const float SC = (1.0f - 0.1f) / 8.0f;
    #pragma unroll
    for (int ni = 0; ni < 4; ++ni) {
        const int col = n0 + wn + ni * 16 + l15;
        const bool isQ = (col < 768);
        const float bv = isQ ? bq[col] : bk[col - 768];
        const float sc = isQ ? SC : 1.0f;
        #pragma unroll
        for (int mi = 0; mi < 4; ++mi)
            #pragma unroll
            for (int r = 0; r < 4; ++r) {
                const int row = m0 + wm + mi * 16 + quad * 4 + r;
                QK[(size_t)row * 1536 + col] = (f16)((acc[mi][ni][r] + bv) * sc);
            }
    }
}

// ---------------------------------------------------------------------------
// attn: block = (b, qt, head-group); 384 thr = 6 waves, wave w -> head hg*6+w,
// 16 q-rows. SWAPPED mfma(K,Q): D[col=q=l15][row=k=quad*4+r], k-tile t adds 16t.
// Per lane: one q row, k = 16t + 4*quad + r  -> float4 dep reads, 2-shfl
// softmax, direct float4 stores. dep LDS tile shared by 6 heads; barrier
// deferred past MFMA. grid (32, 2, 8) = 512 blocks. At the 402.7MB store floor.
__global__ __launch_bounds__(384, 2)
void attn_mfma(const f16* __restrict__ QK, const float* __restrict__ dep,
               const int* __restrict__ mask, float* __restrict__ out) {
    const int qt = blockIdx.x;        // 0..31
    const int hg = blockIdx.y;        // 0..1
    const int b  = blockIdx.z;        // 0..7
    const int tid = threadIdx.x;
    const int wid = tid >> 6;         // 0..5
    const int l   = tid & 63;
    const int l15 = l & 15, quad = l >> 4;
    const int h  = hg * 6 + wid;
    const int q0 = qt * 16;

    __shared__ float depL[16 * DEPS];        // 33.0 KB

    // stage dep tile: 16 rows x 512 cols (2048 float4, block-cooperative).
    // barrier deferred until after the MFMA loop (stage latency hides under MFMA).
    {
        const float* __restrict__ src = dep + ((size_t)b * NTOK + q0) * NTOK;
        #pragma unroll
        for (int i = 0; i < 6; ++i) {
            const int idx = tid + i * 384;
            if (idx < 2048) {
                const int row = idx >> 7, c4 = idx & 127;
                float4 v = *(const float4*)&src[(size_t)row * NTOK + c4 * 4];
                *(float4*)&depL[row * DEPS + c4 * 4] = v;
            }
        }
    }

    f32x4 acc[32];
    #pragma unroll
    for (int t = 0; t < 32; ++t) acc[t] = (f32x4){0.f, 0.f, 0.f, 0.f};

    // Q as B-fragment: B[col=l15 -> q row][k=quad*8+j]; Q pre-scaled 0.9/8 in proj
    const f16* __restrict__ Qb = QK + (size_t)(b * NTOK + q0 + l15) * 1536 + h * 64 + quad * 8;
    const f16x8 qf0 = *(const f16x8*)(Qb);
    const f16x8 qf1 = *(const f16x8*)(Qb + 32);

    // K as A-fragment: A[row=l15 -> key within tile][k=quad*8+j], from L2
    const f16* __restrict__ Kb = QK + (size_t)(b * NTOK + l15) * 1536 + 768 + h * 64 + quad * 8;
    #pragma unroll
    for (int t = 0; t < 32; ++t) {
        f16x8 k0 = *(const f16x8*)(Kb + (size_t)(t * 16) * 1536);
        acc[t] = __builtin_amdgcn_mfma_f32_16x16x32_f16(k0, qf0, acc[t], 0, 0, 0);
        f16x8 k1 = *(const f16x8*)(Kb + (size_t)(t * 16) * 1536 + 32);
        acc[t] = __builtin_amdgcn_mfma_f32_16x16x32_f16(k1, qf1, acc[t], 0, 0, 0);
    }

    __syncthreads();   // dep tile staged by all waves

    // blend (float4 dep from LDS) + mask + row-max, single pass.
    // lane's k for (t, r) = t*16 + quad*4 + r
    const float DW = 0.1f;
    const int* __restrict__ mrow = mask + b * NTOK;
    float m = NEGV;
    #pragma unroll
    for (int t = 0; t < 32; ++t) {
        const int kc = t * 16 + quad * 4;
        const f32x4 dv = *(const f32x4*)&depL[l15 * DEPS + kc];
        const int4  mv = *(const int4*)&mrow[kc];
        const float s0 = acc[t][0] + DW * dv[0];
        const float s1 = acc[t][1] + DW * dv[1];
        const float s2 = acc[t][2] + DW * dv[2];
        const float s3 = acc[t][3] + DW * dv[3];
        acc[t][0] = mv.x ? s0 : NEGV;
        acc[t][1] = mv.y ? s1 : NEGV;
        acc[t][2] = mv.z ? s2 : NEGV;
        acc[t][3] = mv.w ? s3 : NEGV;
        m = fmaxf(m, fmaxf(fmaxf(acc[t][0], acc[t][1]), fmaxf(acc[t][2], acc[t][3])));
    }
    // q row lives in lanes {l15, l15+16, l15+32, l15+48}
    m = fmaxf(m, __shfl_xor(m, 16));
    m = fmaxf(m, __shfl_xor(m, 32));

    float sum = 0.f;
    #pragma unroll
    for (int t = 0; t < 32; ++t) {
        #pragma unroll
        for (int r = 0; r < 4; ++r) {
            const float e = __expf(acc[t][r] - m);
            acc[t][r] = e;
            sum += e;
        }
    }
    sum += __shfl_xor(sum, 16);
    sum += __shfl_xor(sum, 32);
    const float inv = 1.0f / sum;

    // epilogue: direct float4 stores. out[b][h][q0+l15][16t + 4*quad + r]
    const size_t obase = ((size_t)((b * NHEAD + h) * NTOK) + q0 + l15) * NTOK + quad * 4;
    #pragma unroll
    for (int t = 0; t < 32; ++t) {
        f32x4 v = acc[t] * inv;
        *(f32x4*)&out[obase + (size_t)t * 16] = v;
    }
}

// ---------------------------------------------------------------------------
extern "C" void kernel_launch(void* const* d_in, const int* in_sizes, int n_in,
                              void* d_out, int out_size, void* d_ws, size_t ws_size,
                              hipStream_t stream) {
    const float* X    = (const float*)d_in[0];
    const int*   mask = (const int*)  d_in[1];
    const float* dep  = (const float*)d_in[2];
    const float* Wq   = (const float*)d_in[3];
    const float* bq   = (const float*)d_in[4];
    const float* Wk   = (const float*)d_in[5];
    const float* bk   = (const float*)d_in[6];
    float* out = (float*)d_out;

    f16* Xh = (f16*)d_ws;                                  // 4096*768
    f16* Wt = Xh + (size_t)BATCH * NTOK * DMODEL;          // 1536*768
    f16* QK = Wt + (size_t)1536 * DMODEL;                  // 4096*1536

    prep_kernel<<<dim3(3072 + 1152), 256, 0, stream>>>(X, Xh, Wq, Wk, Wt);
    proj_mfma<<<dim3(4096 / 128, 1536 / 128), 256, 0, stream>>>(Xh, Wt, bq, bk, QK);
    attn_mfma<<<dim3(32, 2, BATCH), 384, 0, stream>>>(QK, dep, mask, out);
}